// Round 1
// 266.727 us; speedup vs baseline: 1.0134x; 1.0134x over previous
//
#include <hip/hip_runtime.h>

typedef _Float16 h2_t __attribute__((ext_vector_type(2)));

static __device__ __forceinline__ unsigned short f2h_bits(float x) {
    return __builtin_bit_cast(unsigned short, (_Float16)x);
}
static __device__ __forceinline__ unsigned pack_h2(float x, float y) {
    h2_t v = {(_Float16)x, (_Float16)y};
    return __builtin_bit_cast(unsigned, v);
}
// acc += a.x*b.x + a.y*b.y  (v_dot2_f32_f16, fp32 accumulate)
static __device__ __forceinline__ float dot2f(unsigned a, unsigned b, float c) {
#if __has_builtin(__builtin_amdgcn_fdot2)
    return __builtin_amdgcn_fdot2(__builtin_bit_cast(h2_t, a),
                                  __builtin_bit_cast(h2_t, b), c, false);
#else
    const h2_t ha = __builtin_bit_cast(h2_t, a), hb = __builtin_bit_cast(h2_t, b);
    return fmaf((float)ha[1], (float)hb[1], fmaf((float)ha[0], (float)hb[0], c));
#endif
}
// packed-f16 xor-shuffle add (v_pk_add_f16 + ds_swizzle/bpermute)
static __device__ __forceinline__ h2_t shx_add(h2_t v, int m) {
    return v + __builtin_bit_cast(h2_t, __shfl_xor(__builtin_bit_cast(int, v), m, 64));
}

// Prologue: feats2[t][:] = f16(feats[nid2[t]][:]) for t in [0,N2).
// lane=(sub<<4)|c4; quarter-wave `sub` handles one row; lane moves 4 cols.
__global__ __launch_bounds__(256) void k_cast(
    const float* __restrict__ feats,     // [V,64] fp32
    const int*   __restrict__ nid2,      // [N2]
    unsigned short* __restrict__ feats2, // [N2,64] f16 bits
    int N2)
{
    const int lane = threadIdx.x & 63;
    const int sub  = lane >> 4;
    const int c4   = lane & 15;
    const int gwave = blockIdx.x * (blockDim.x >> 6) + (threadIdx.x >> 6);
    const int nwave = gridDim.x * (blockDim.x >> 6);

    for (int base = 8 * gwave; base < N2; base += 8 * nwave) {
        const int t0 = base + sub;
        const int t1 = base + 4 + sub;
        const bool v0 = (t0 < N2), v1 = (t1 < N2);
        const int n0 = v0 ? nid2[t0] : 0;
        const int n1 = v1 ? nid2[t1] : 0;
        const float4 a = ((const float4*)feats)[(size_t)n0 * 16 + c4];
        const float4 b = ((const float4*)feats)[(size_t)n1 * 16 + c4];
        ushort4 sa, sb;
        sa.x = f2h_bits(a.x); sa.y = f2h_bits(a.y);
        sa.z = f2h_bits(a.z); sa.w = f2h_bits(a.w);
        sb.x = f2h_bits(b.x); sb.y = f2h_bits(b.y);
        sb.z = f2h_bits(b.z); sb.w = f2h_bits(b.w);
        if (v0) ((ushort4*)feats2)[(size_t)t0 * 16 + c4] = sa;
        if (v1) ((ushort4*)feats2)[(size_t)t1 * 16 + c4] = sb;
    }
}

// Hop-1: agg = mean_k table[idx (or nid2[idx])], h1 = relu(agg@W0+b0) -> f16.
// Gather-sum in packed f16 (v_pk_add_f16); matmul via readlane of packed agg
// pairs + v_dot2_f32_f16 against pre-packed (W0/32) pairs.
template <bool IND, typename TT>
__global__ __launch_bounds__(256) void k_hop1(
    const TT*    __restrict__ table,  // feats2 (f16) or feats (fp32)
    const float* __restrict__ W0,     // [64,64]
    const float* __restrict__ b0,     // [64]
    const int*   __restrict__ idx1,   // [N1,32]
    const int*   __restrict__ nid2,   // [N2] (used iff IND)
    unsigned short* __restrict__ h1,  // [N1,64] f16 out
    int N1)
{
    const int lane = threadIdx.x & 63;
    const int sub  = lane >> 4;
    const int c4   = lane & 15;
    const int gwave = blockIdx.x * (blockDim.x >> 6) + (threadIdx.x >> 6);
    const int nwave = gridDim.x * (blockDim.x >> 6);

    // W0 pairs along d, pre-scaled by 1/32 (mean fold), packed f16.
    unsigned w0p[32];
#pragma unroll
    for (int p = 0; p < 32; ++p)
        w0p[p] = pack_h2(W0[(2 * p) * 64 + lane] * 0.03125f,
                         (2 * p + 1 < 64 ? W0[(2 * p + 1) * 64 + lane] : 0.f) * 0.03125f);
    const float bias = b0[lane];

    const int4* iv = (const int4*)idx1;   // [N1, 8] int4

    for (int base = 2 * gwave; base < N1; base += 2 * nwave) {
        const int r0 = base;
        const bool has_r1 = (base + 1 < N1);
        const int r1 = has_r1 ? base + 1 : base;

        // 8 neighbor indices per quarter-wave as two int4 loads per row.
        const int4 qa0 = iv[(size_t)r0 * 8 + 2 * sub];
        const int4 qb0 = iv[(size_t)r0 * 8 + 2 * sub + 1];
        const int4 qa1 = iv[(size_t)r1 * 8 + 2 * sub];
        const int4 qb1 = iv[(size_t)r1 * 8 + 2 * sub + 1];
        int nk0[8] = {qa0.x, qa0.y, qa0.z, qa0.w, qb0.x, qb0.y, qb0.z, qb0.w};
        int nk1[8] = {qa1.x, qa1.y, qa1.z, qa1.w, qb1.x, qb1.y, qb1.z, qb1.w};
        if constexpr (IND) {
#pragma unroll
            for (int i = 0; i < 8; ++i) {
                nk0[i] = nid2[nk0[i]];
                nk1[i] = nid2[nk1[i]];
            }
        }

        unsigned pk00, pk01, pk10, pk11;  // packed f16 neighbor sums (4 cols/lane)
        if constexpr (!IND) {
            // f16 table: 16 gathers in flight, 2 v_pk_add_f16 per 8B load.
            h2_t a00 = {0, 0}, a01 = {0, 0}, a10 = {0, 0}, a11 = {0, 0};
#pragma unroll
            for (int i = 0; i < 8; ++i) {
                const uint2 v0 = ((const uint2*)table)[(size_t)nk0[i] * 16 + c4];
                const uint2 v1 = ((const uint2*)table)[(size_t)nk1[i] * 16 + c4];
                a00 += __builtin_bit_cast(h2_t, v0.x);
                a01 += __builtin_bit_cast(h2_t, v0.y);
                a10 += __builtin_bit_cast(h2_t, v1.x);
                a11 += __builtin_bit_cast(h2_t, v1.y);
            }
            // combine quarter-wave partials (packed)
            a00 = shx_add(a00, 16); a00 = shx_add(a00, 32);
            a01 = shx_add(a01, 16); a01 = shx_add(a01, 32);
            a10 = shx_add(a10, 16); a10 = shx_add(a10, 32);
            a11 = shx_add(a11, 16); a11 = shx_add(a11, 32);
            pk00 = __builtin_bit_cast(unsigned, a00);
            pk01 = __builtin_bit_cast(unsigned, a01);
            pk10 = __builtin_bit_cast(unsigned, a10);
            pk11 = __builtin_bit_cast(unsigned, a11);
        } else {
            // fp32 table fallback
            float a0[4] = {0.f, 0.f, 0.f, 0.f};
            float a1[4] = {0.f, 0.f, 0.f, 0.f};
#pragma unroll
            for (int i = 0; i < 8; ++i) {
                const float4 v0 = ((const float4*)table)[(size_t)nk0[i] * 16 + c4];
                const float4 v1 = ((const float4*)table)[(size_t)nk1[i] * 16 + c4];
                a0[0] += v0.x; a0[1] += v0.y; a0[2] += v0.z; a0[3] += v0.w;
                a1[0] += v1.x; a1[1] += v1.y; a1[2] += v1.z; a1[3] += v1.w;
            }
#pragma unroll
            for (int c = 0; c < 4; ++c) {
                a0[c] += __shfl_xor(a0[c], 16, 64);
                a0[c] += __shfl_xor(a0[c], 32, 64);
                a1[c] += __shfl_xor(a1[c], 16, 64);
                a1[c] += __shfl_xor(a1[c], 32, 64);
            }
            pk00 = __builtin_bit_cast(unsigned, __builtin_amdgcn_cvt_pkrtz(a0[0], a0[1]));
            pk01 = __builtin_bit_cast(unsigned, __builtin_amdgcn_cvt_pkrtz(a0[2], a0[3]));
            pk10 = __builtin_bit_cast(unsigned, __builtin_amdgcn_cvt_pkrtz(a1[0], a1[1]));
            pk11 = __builtin_bit_cast(unsigned, __builtin_amdgcn_cvt_pkrtz(a1[2], a1[3]));
        }

        // h[lane] = relu(b[lane] + sum_p dot2(aggpair_p, (W0/32)pair_p[lane]))
        float h0 = bias, h1v = bias;
#pragma unroll
        for (int p = 0; p < 32; ++p) {
            const unsigned a0p = (unsigned)__builtin_amdgcn_readlane(
                (int)(p & 1 ? pk01 : pk00), p >> 1);
            const unsigned a1p = (unsigned)__builtin_amdgcn_readlane(
                (int)(p & 1 ? pk11 : pk10), p >> 1);
            h0  = dot2f(a0p, w0p[p], h0);
            h1v = dot2f(a1p, w0p[p], h1v);
        }
        h0  = fmaxf(h0, 0.f);
        h1v = fmaxf(h1v, 0.f);

        h1[(size_t)r0 * 64 + lane] = f2h_bits(h0);
        if (has_r1) h1[(size_t)r1 * 64 + lane] = f2h_bits(h1v);
    }
}

// Seed layer: gather-mean over f16 h1 rows (packed adds), W1 via dot2, fp32 out.
__global__ __launch_bounds__(256) void k_hop0(
    const unsigned short* __restrict__ h1,  // [N1,64] f16
    const float* __restrict__ W1,     // [64,64]
    const float* __restrict__ b1,     // [64]
    const int*   __restrict__ idx0,   // [N0,32]
    float*       __restrict__ out,    // [N0,64] fp32
    int N0)
{
    const int lane = threadIdx.x & 63;
    const int sub  = lane >> 4;
    const int c4   = lane & 15;
    const int gwave = blockIdx.x * (blockDim.x >> 6) + (threadIdx.x >> 6);
    const int nwave = gridDim.x * (blockDim.x >> 6);

    unsigned w1p[32];
#pragma unroll
    for (int p = 0; p < 32; ++p)
        w1p[p] = pack_h2(W1[(2 * p) * 64 + lane] * 0.03125f,
                         (2 * p + 1 < 64 ? W1[(2 * p + 1) * 64 + lane] : 0.f) * 0.03125f);
    const float bias = b1[lane];

    const int4* iv = (const int4*)idx0;   // [N0, 8] int4

    for (int base = 2 * gwave; base < N0; base += 2 * nwave) {
        const int r0 = base;
        const bool has_r1 = (base + 1 < N0);
        const int r1 = has_r1 ? base + 1 : base;

        const int4 qa0 = iv[(size_t)r0 * 8 + 2 * sub];
        const int4 qb0 = iv[(size_t)r0 * 8 + 2 * sub + 1];
        const int4 qa1 = iv[(size_t)r1 * 8 + 2 * sub];
        const int4 qb1 = iv[(size_t)r1 * 8 + 2 * sub + 1];
        const int jk0[8] = {qa0.x, qa0.y, qa0.z, qa0.w, qb0.x, qb0.y, qb0.z, qb0.w};
        const int jk1[8] = {qa1.x, qa1.y, qa1.z, qa1.w, qb1.x, qb1.y, qb1.z, qb1.w};

        h2_t a00 = {0, 0}, a01 = {0, 0}, a10 = {0, 0}, a11 = {0, 0};
#pragma unroll
        for (int i = 0; i < 8; ++i) {
            const uint2 v0 = ((const uint2*)h1)[(size_t)jk0[i] * 16 + c4];
            const uint2 v1 = ((const uint2*)h1)[(size_t)jk1[i] * 16 + c4];
            a00 += __builtin_bit_cast(h2_t, v0.x);
            a01 += __builtin_bit_cast(h2_t, v0.y);
            a10 += __builtin_bit_cast(h2_t, v1.x);
            a11 += __builtin_bit_cast(h2_t, v1.y);
        }
        a00 = shx_add(a00, 16); a00 = shx_add(a00, 32);
        a01 = shx_add(a01, 16); a01 = shx_add(a01, 32);
        a10 = shx_add(a10, 16); a10 = shx_add(a10, 32);
        a11 = shx_add(a11, 16); a11 = shx_add(a11, 32);
        const unsigned pk00 = __builtin_bit_cast(unsigned, a00);
        const unsigned pk01 = __builtin_bit_cast(unsigned, a01);
        const unsigned pk10 = __builtin_bit_cast(unsigned, a10);
        const unsigned pk11 = __builtin_bit_cast(unsigned, a11);

        float o0 = bias, o1 = bias;
#pragma unroll
        for (int p = 0; p < 32; ++p) {
            const unsigned a0p = (unsigned)__builtin_amdgcn_readlane(
                (int)(p & 1 ? pk01 : pk00), p >> 1);
            const unsigned a1p = (unsigned)__builtin_amdgcn_readlane(
                (int)(p & 1 ? pk11 : pk10), p >> 1);
            o0 = dot2f(a0p, w1p[p], o0);
            o1 = dot2f(a1p, w1p[p], o1);
        }
        out[(size_t)r0 * 64 + lane] = fmaxf(o0, 0.f);
        if (has_r1) out[(size_t)r1 * 64 + lane] = fmaxf(o1, 0.f);
    }
}

extern "C" void kernel_launch(void* const* d_in, const int* in_sizes, int n_in,
                              void* d_out, int out_size, void* d_ws, size_t ws_size,
                              hipStream_t stream) {
    const float* feats = (const float*)d_in[0];
    const float* W0    = (const float*)d_in[1];
    const float* b0    = (const float*)d_in[2];
    const float* W1    = (const float*)d_in[3];
    const float* b1    = (const float*)d_in[4];
    const int*   idx0  = (const int*)d_in[5];   // [N0,32]
    const int*   idx1  = (const int*)d_in[6];   // [N1,32]
    // d_in[7] = node_ids1 — dead in the reference (v1 unused)
    const int*   nid2  = (const int*)d_in[8];   // [N2]

    const int N0 = in_sizes[5] / 32;            // 8192
    const int N1 = in_sizes[6] / 32;            // 100000
    const int N2 = in_sizes[8];                 // 300000

    const size_t bytes_feats2 = (size_t)N2 * 64 * 2;   // 38.4 MB
    const size_t bytes_h1     = (size_t)N1 * 64 * 2;   // 12.8 MB

    if (ws_size >= bytes_feats2 + bytes_h1) {
        unsigned short* feats2 = (unsigned short*)d_ws;
        unsigned short* h1     = (unsigned short*)((char*)d_ws + bytes_feats2);
        k_cast<<<2048, 256, 0, stream>>>(feats, nid2, feats2, N2);
        k_hop1<false, unsigned short><<<2048, 256, 0, stream>>>(
            feats2, W0, b0, idx1, nullptr, h1, N1);
        k_hop0<<<1024, 256, 0, stream>>>(h1, W1, b1, idx0, (float*)d_out, N0);
    } else {
        unsigned short* h1 = (unsigned short*)d_ws;
        k_hop1<true, float><<<2048, 256, 0, stream>>>(
            feats, W0, b0, idx1, nid2, h1, N1);
        k_hop0<<<1024, 256, 0, stream>>>(h1, W1, b1, idx0, (float*)d_out, N0);
    }
}

// Round 2
// 264.434 us; speedup vs baseline: 1.0222x; 1.0087x over previous
//
#include <hip/hip_runtime.h>

typedef _Float16 h2_t __attribute__((ext_vector_type(2)));

static __device__ __forceinline__ unsigned short f2h_bits(float x) {
    return __builtin_bit_cast(unsigned short, (_Float16)x);
}
static __device__ __forceinline__ unsigned pack_h2(float x, float y) {
    h2_t v = {(_Float16)x, (_Float16)y};
    return __builtin_bit_cast(unsigned, v);
}
// acc += a.x*b.x + a.y*b.y  (v_dot2_f32_f16, fp32 accumulate)
static __device__ __forceinline__ float dot2f(unsigned a, unsigned b, float c) {
#if __has_builtin(__builtin_amdgcn_fdot2)
    return __builtin_amdgcn_fdot2(__builtin_bit_cast(h2_t, a),
                                  __builtin_bit_cast(h2_t, b), c, false);
#else
    const h2_t ha = __builtin_bit_cast(h2_t, a), hb = __builtin_bit_cast(h2_t, b);
    return fmaf((float)ha[1], (float)hb[1], fmaf((float)ha[0], (float)hb[0], c));
#endif
}
// packed-f16 xor-shuffle add
static __device__ __forceinline__ h2_t shx_add(h2_t v, int m) {
    return v + __builtin_bit_cast(h2_t, __shfl_xor(__builtin_bit_cast(int, v), m, 64));
}

// Prologue: feats2[t][:] = f16(feats[nid2[t]][:]); 16 rows/iter/wave, 4 loads in flight.
__global__ __launch_bounds__(256) void k_cast(
    const float* __restrict__ feats,     // [V,64] fp32
    const int*   __restrict__ nid2,      // [N2]
    unsigned short* __restrict__ feats2, // [N2,64] f16 bits
    int N2)
{
    const int lane = threadIdx.x & 63;
    const int sub  = lane >> 4;
    const int c4   = lane & 15;
    const int gwave = blockIdx.x * (blockDim.x >> 6) + (threadIdx.x >> 6);
    const int nwave = gridDim.x * (blockDim.x >> 6);

    for (int base = 16 * gwave; base < N2; base += 16 * nwave) {
        int t[4]; bool vv[4]; int n[4];
#pragma unroll
        for (int s = 0; s < 4; ++s) {
            t[s]  = base + 4 * s + sub;
            vv[s] = t[s] < N2;
            n[s]  = vv[s] ? nid2[t[s]] : 0;
        }
        float4 a[4];
#pragma unroll
        for (int s = 0; s < 4; ++s)
            a[s] = ((const float4*)feats)[(size_t)n[s] * 16 + c4];
#pragma unroll
        for (int s = 0; s < 4; ++s) {
            ushort4 sa;
            sa.x = f2h_bits(a[s].x); sa.y = f2h_bits(a[s].y);
            sa.z = f2h_bits(a[s].z); sa.w = f2h_bits(a[s].w);
            if (vv[s]) ((ushort4*)feats2)[(size_t)t[s] * 16 + c4] = sa;
        }
    }
}

// Hop-1 (f16 table): 2 output rows per wave-iter.
// lane = (hi<<5)|(g4<<3)|c8 : hi picks output row, g4 picks an 8-neighbor block,
// c8 picks a 16B chunk (8 f16) of the gathered row -> dwordx4 gathers, 8 rows/instr.
// Next iteration's gathers are issued before the current reduce/matmul (latency hiding).
// W0 lives in LDS as packed-f16 pairs pre-scaled by 1/32.
__global__ __launch_bounds__(256, 4) void k_hop1_f16(
    const unsigned short* __restrict__ table, // [N2,64] f16
    const float* __restrict__ W0,             // [64,64]
    const float* __restrict__ b0,             // [64]
    const int*   __restrict__ idx1,           // [N1,32]
    unsigned short* __restrict__ h1,          // [N1,64] f16 out
    int N1)
{
    __shared__ unsigned wlds[32 * 64];
    for (int e = threadIdx.x; e < 2048; e += 256) {
        const int p = e >> 6, l = e & 63;
        wlds[e] = pack_h2(W0[(2 * p) * 64 + l] * 0.03125f,
                          W0[(2 * p + 1) * 64 + l] * 0.03125f);
    }
    __syncthreads();

    const int lane = threadIdx.x & 63;
    const int g4   = (lane >> 3) & 3;
    const int hi   = lane >> 5;
    const int c8   = lane & 7;
    const float bias = b0[lane];
    const int gwave = blockIdx.x * (blockDim.x >> 6) + (threadIdx.x >> 6);
    const int nwave = gridDim.x * (blockDim.x >> 6);

    const int4*  iv = (const int4*)idx1;   // [N1, 8] int4
    const uint4* tp = (const uint4*)table; // [N2, 8] uint4 (16B chunks)

    int base = 2 * gwave;
    if (base >= N1) return;

    uint4 v[8];
    {
        const int rr = (base + 1 < N1) ? base + hi : base;
        const int4 qa = iv[(size_t)rr * 8 + 2 * g4];
        const int4 qb = iv[(size_t)rr * 8 + 2 * g4 + 1];
        const int nk[8] = {qa.x, qa.y, qa.z, qa.w, qb.x, qb.y, qb.z, qb.w};
#pragma unroll
        for (int i = 0; i < 8; ++i)
            v[i] = tp[(size_t)nk[i] * 8 + c8];
    }

    for (;;) {
        const int nxt = base + 2 * nwave;
        const bool more = nxt < N1;
        uint4 w[8];
        if (more) {  // prefetch next iteration's gathers
            const int rr = (nxt + 1 < N1) ? nxt + hi : nxt;
            const int4 qa = iv[(size_t)rr * 8 + 2 * g4];
            const int4 qb = iv[(size_t)rr * 8 + 2 * g4 + 1];
            const int nk[8] = {qa.x, qa.y, qa.z, qa.w, qb.x, qb.y, qb.z, qb.w};
#pragma unroll
            for (int i = 0; i < 8; ++i)
                w[i] = tp[(size_t)nk[i] * 8 + c8];
        }

        // ---- consume current iteration ----
        h2_t acc[4] = {h2_t{0, 0}, h2_t{0, 0}, h2_t{0, 0}, h2_t{0, 0}};
#pragma unroll
        for (int i = 0; i < 8; ++i) {
            acc[0] += __builtin_bit_cast(h2_t, v[i].x);
            acc[1] += __builtin_bit_cast(h2_t, v[i].y);
            acc[2] += __builtin_bit_cast(h2_t, v[i].z);
            acc[3] += __builtin_bit_cast(h2_t, v[i].w);
        }
#pragma unroll
        for (int j = 0; j < 4; ++j) {
            acc[j] = shx_add(acc[j], 8);
            acc[j] = shx_add(acc[j], 16);
        }
        // lanes 0-31 hold row `base` sums (cols 8*c8..8*c8+8 as 4 h2 pairs),
        // lanes 32-63 hold row `base+1` sums.
        float h0a = bias, h0b = 0.f, h1a = bias, h1b = 0.f;
#pragma unroll
        for (int p = 0; p < 32; ++p) {
            const unsigned wp = wlds[p * 64 + lane];
            const int av = __builtin_bit_cast(int, acc[p & 3]);
            const unsigned a0 = (unsigned)__builtin_amdgcn_readlane(av, p >> 2);
            const unsigned a1 = (unsigned)__builtin_amdgcn_readlane(av, 32 + (p >> 2));
            if (p & 1) { h0b = dot2f(a0, wp, h0b); h1b = dot2f(a1, wp, h1b); }
            else       { h0a = dot2f(a0, wp, h0a); h1a = dot2f(a1, wp, h1a); }
        }
        h1[(size_t)base * 64 + lane] = f2h_bits(fmaxf(h0a + h0b, 0.f));
        if (base + 1 < N1)
            h1[(size_t)(base + 1) * 64 + lane] = f2h_bits(fmaxf(h1a + h1b, 0.f));

        if (!more) break;
#pragma unroll
        for (int i = 0; i < 8; ++i) v[i] = w[i];
        base = nxt;
    }
}

// Fallback hop-1 (fp32 table, double indirection) — only if ws can't hold feats2.
__global__ __launch_bounds__(256) void k_hop1_f32(
    const float* __restrict__ table,  // feats fp32 [V,64]
    const float* __restrict__ W0,
    const float* __restrict__ b0,
    const int*   __restrict__ idx1,
    const int*   __restrict__ nid2,
    unsigned short* __restrict__ h1,
    int N1)
{
    const int lane = threadIdx.x & 63;
    const int sub  = lane >> 4;
    const int c4   = lane & 15;
    const int gwave = blockIdx.x * (blockDim.x >> 6) + (threadIdx.x >> 6);
    const int nwave = gridDim.x * (blockDim.x >> 6);

    unsigned w0p[32];
#pragma unroll
    for (int p = 0; p < 32; ++p)
        w0p[p] = pack_h2(W0[(2 * p) * 64 + lane] * 0.03125f,
                         W0[(2 * p + 1) * 64 + lane] * 0.03125f);
    const float bias = b0[lane];
    const int4* iv = (const int4*)idx1;

    for (int base = 2 * gwave; base < N1; base += 2 * nwave) {
        const int r0 = base;
        const bool has_r1 = (base + 1 < N1);
        const int r1 = has_r1 ? base + 1 : base;
        const int4 qa0 = iv[(size_t)r0 * 8 + 2 * sub];
        const int4 qb0 = iv[(size_t)r0 * 8 + 2 * sub + 1];
        const int4 qa1 = iv[(size_t)r1 * 8 + 2 * sub];
        const int4 qb1 = iv[(size_t)r1 * 8 + 2 * sub + 1];
        int nk0[8] = {qa0.x, qa0.y, qa0.z, qa0.w, qb0.x, qb0.y, qb0.z, qb0.w};
        int nk1[8] = {qa1.x, qa1.y, qa1.z, qa1.w, qb1.x, qb1.y, qb1.z, qb1.w};
#pragma unroll
        for (int i = 0; i < 8; ++i) { nk0[i] = nid2[nk0[i]]; nk1[i] = nid2[nk1[i]]; }

        float a0[4] = {0.f, 0.f, 0.f, 0.f};
        float a1[4] = {0.f, 0.f, 0.f, 0.f};
#pragma unroll
        for (int i = 0; i < 8; ++i) {
            const float4 v0 = ((const float4*)table)[(size_t)nk0[i] * 16 + c4];
            const float4 v1 = ((const float4*)table)[(size_t)nk1[i] * 16 + c4];
            a0[0] += v0.x; a0[1] += v0.y; a0[2] += v0.z; a0[3] += v0.w;
            a1[0] += v1.x; a1[1] += v1.y; a1[2] += v1.z; a1[3] += v1.w;
        }
#pragma unroll
        for (int c = 0; c < 4; ++c) {
            a0[c] += __shfl_xor(a0[c], 16, 64);
            a0[c] += __shfl_xor(a0[c], 32, 64);
            a1[c] += __shfl_xor(a1[c], 16, 64);
            a1[c] += __shfl_xor(a1[c], 32, 64);
        }
        const unsigned pk00 = __builtin_bit_cast(unsigned, __builtin_amdgcn_cvt_pkrtz(a0[0], a0[1]));
        const unsigned pk01 = __builtin_bit_cast(unsigned, __builtin_amdgcn_cvt_pkrtz(a0[2], a0[3]));
        const unsigned pk10 = __builtin_bit_cast(unsigned, __builtin_amdgcn_cvt_pkrtz(a1[0], a1[1]));
        const unsigned pk11 = __builtin_bit_cast(unsigned, __builtin_amdgcn_cvt_pkrtz(a1[2], a1[3]));

        float h0 = bias, h1v = bias;
#pragma unroll
        for (int p = 0; p < 32; ++p) {
            const unsigned a0p = (unsigned)__builtin_amdgcn_readlane(
                (int)(p & 1 ? pk01 : pk00), p >> 1);
            const unsigned a1p = (unsigned)__builtin_amdgcn_readlane(
                (int)(p & 1 ? pk11 : pk10), p >> 1);
            h0  = dot2f(a0p, w0p[p], h0);
            h1v = dot2f(a1p, w0p[p], h1v);
        }
        h1[(size_t)r0 * 64 + lane] = f2h_bits(fmaxf(h0, 0.f));
        if (has_r1) h1[(size_t)r1 * 64 + lane] = f2h_bits(fmaxf(h1v, 0.f));
    }
}

// Seed layer: same x4-gather structure as hop1 (no prefetch; tiny kernel), fp32 out.
__global__ __launch_bounds__(256, 4) void k_hop0(
    const unsigned short* __restrict__ h1t,  // [N1,64] f16
    const float* __restrict__ W1,            // [64,64]
    const float* __restrict__ b1,            // [64]
    const int*   __restrict__ idx0,          // [N0,32]
    float*       __restrict__ out,           // [N0,64] fp32
    int N0)
{
    __shared__ unsigned wlds[32 * 64];
    for (int e = threadIdx.x; e < 2048; e += 256) {
        const int p = e >> 6, l = e & 63;
        wlds[e] = pack_h2(W1[(2 * p) * 64 + l] * 0.03125f,
                          W1[(2 * p + 1) * 64 + l] * 0.03125f);
    }
    __syncthreads();

    const int lane = threadIdx.x & 63;
    const int g4   = (lane >> 3) & 3;
    const int hi   = lane >> 5;
    const int c8   = lane & 7;
    const float bias = b1[lane];
    const int gwave = blockIdx.x * (blockDim.x >> 6) + (threadIdx.x >> 6);
    const int nwave = gridDim.x * (blockDim.x >> 6);

    const int4*  iv = (const int4*)idx0;
    const uint4* tp = (const uint4*)h1t;

    for (int base = 2 * gwave; base < N0; base += 2 * nwave) {
        const int rr = (base + 1 < N0) ? base + hi : base;
        const int4 qa = iv[(size_t)rr * 8 + 2 * g4];
        const int4 qb = iv[(size_t)rr * 8 + 2 * g4 + 1];
        const int nk[8] = {qa.x, qa.y, qa.z, qa.w, qb.x, qb.y, qb.z, qb.w};

        uint4 v[8];
#pragma unroll
        for (int i = 0; i < 8; ++i)
            v[i] = tp[(size_t)nk[i] * 8 + c8];

        h2_t acc[4] = {h2_t{0, 0}, h2_t{0, 0}, h2_t{0, 0}, h2_t{0, 0}};
#pragma unroll
        for (int i = 0; i < 8; ++i) {
            acc[0] += __builtin_bit_cast(h2_t, v[i].x);
            acc[1] += __builtin_bit_cast(h2_t, v[i].y);
            acc[2] += __builtin_bit_cast(h2_t, v[i].z);
            acc[3] += __builtin_bit_cast(h2_t, v[i].w);
        }
#pragma unroll
        for (int j = 0; j < 4; ++j) {
            acc[j] = shx_add(acc[j], 8);
            acc[j] = shx_add(acc[j], 16);
        }
        float o0a = bias, o0b = 0.f, o1a = bias, o1b = 0.f;
#pragma unroll
        for (int p = 0; p < 32; ++p) {
            const unsigned wp = wlds[p * 64 + lane];
            const int av = __builtin_bit_cast(int, acc[p & 3]);
            const unsigned a0 = (unsigned)__builtin_amdgcn_readlane(av, p >> 2);
            const unsigned a1 = (unsigned)__builtin_amdgcn_readlane(av, 32 + (p >> 2));
            if (p & 1) { o0b = dot2f(a0, wp, o0b); o1b = dot2f(a1, wp, o1b); }
            else       { o0a = dot2f(a0, wp, o0a); o1a = dot2f(a1, wp, o1a); }
        }
        out[(size_t)base * 64 + lane] = fmaxf(o0a + o0b, 0.f);
        if (base + 1 < N0)
            out[(size_t)(base + 1) * 64 + lane] = fmaxf(o1a + o1b, 0.f);
    }
}

extern "C" void kernel_launch(void* const* d_in, const int* in_sizes, int n_in,
                              void* d_out, int out_size, void* d_ws, size_t ws_size,
                              hipStream_t stream) {
    const float* feats = (const float*)d_in[0];
    const float* W0    = (const float*)d_in[1];
    const float* b0    = (const float*)d_in[2];
    const float* W1    = (const float*)d_in[3];
    const float* b1    = (const float*)d_in[4];
    const int*   idx0  = (const int*)d_in[5];   // [N0,32]
    const int*   idx1  = (const int*)d_in[6];   // [N1,32]
    // d_in[7] = node_ids1 — dead in the reference (v1 unused)
    const int*   nid2  = (const int*)d_in[8];   // [N2]

    const int N0 = in_sizes[5] / 32;            // 8192
    const int N1 = in_sizes[6] / 32;            // 100000
    const int N2 = in_sizes[8];                 // 300000

    const size_t bytes_feats2 = (size_t)N2 * 64 * 2;   // 38.4 MB
    const size_t bytes_h1     = (size_t)N1 * 64 * 2;   // 12.8 MB

    if (ws_size >= bytes_feats2 + bytes_h1) {
        unsigned short* feats2 = (unsigned short*)d_ws;
        unsigned short* h1     = (unsigned short*)((char*)d_ws + bytes_feats2);
        k_cast<<<2048, 256, 0, stream>>>(feats, nid2, feats2, N2);
        k_hop1_f16<<<2048, 256, 0, stream>>>(feats2, W0, b0, idx1, h1, N1);
        k_hop0<<<1024, 256, 0, stream>>>(h1, W1, b1, idx0, (float*)d_out, N0);
    } else {
        unsigned short* h1 = (unsigned short*)d_ws;
        k_hop1_f32<<<2048, 256, 0, stream>>>(feats, W0, b0, idx1, nid2, h1, N1);
        k_hop0<<<1024, 256, 0, stream>>>(h1, W1, b1, idx0, (float*)d_out, N0);
    }
}

// Round 4
// 257.669 us; speedup vs baseline: 1.0491x; 1.0263x over previous
//
#include <hip/hip_runtime.h>

typedef _Float16 h2_t __attribute__((ext_vector_type(2)));
typedef float    f2_t __attribute__((ext_vector_type(2)));

static __device__ __forceinline__ unsigned short f2h_bits(float x) {
    return __builtin_bit_cast(unsigned short, (_Float16)x);
}
static __device__ __forceinline__ unsigned pack_h2(float x, float y) {
    h2_t v = {(_Float16)x, (_Float16)y};
    return __builtin_bit_cast(unsigned, v);
}
// acc += a.x*b.x + a.y*b.y  (v_dot2_f32_f16, fp32 accumulate)
static __device__ __forceinline__ float dot2f(unsigned a, unsigned b, float c) {
#if __has_builtin(__builtin_amdgcn_fdot2)
    return __builtin_amdgcn_fdot2(__builtin_bit_cast(h2_t, a),
                                  __builtin_bit_cast(h2_t, b), c, false);
#else
    const h2_t ha = __builtin_bit_cast(h2_t, a), hb = __builtin_bit_cast(h2_t, b);
    return fmaf((float)ha[1], (float)hb[1], fmaf((float)ha[0], (float)hb[0], c));
#endif
}

// ---- fp8 e4m3 helpers (hardware cvt on gfx950; software fallback) ----
#if __has_builtin(__builtin_amdgcn_cvt_pk_fp8_f32) && __has_builtin(__builtin_amdgcn_cvt_pk_f32_fp8)
#define FP8_HW 1
#else
#define FP8_HW 0
static __device__ unsigned enc_fp8_sw(float x) {
    const unsigned s = x < 0.f ? 0x80u : 0u;
    float a = fabsf(x);
    if (!(a > 0.f)) return s;
    if (a >= 448.f) return s | 0x7Eu;
    int e; (void)frexpf(a, &e);
    const int E = e - 1;                    // a = m*2^E, m in [1,2)
    if (E < -6) {                           // subnormal, quantum 2^-9
        const int qi = (int)rintf(a * 512.f);
        return qi >= 8 ? (s | 0x08u) : (s | (unsigned)qi);
    }
    int Ee = E;
    int qi = (int)rintf(ldexpf(a, 3 - Ee)); // in [8,16)
    if (qi >= 16) { qi = 8; ++Ee; }
    if (Ee > 8) return s | 0x7Eu;
    return s | ((unsigned)(Ee + 7) << 3) | (unsigned)(qi - 8);
}
static __device__ float dec_fp8_sw(unsigned b) {
    const unsigned e = (b >> 3) & 15u, m = b & 7u;
    const float v = e ? ldexpf((float)(8u + m), (int)e - 10)
                      : ldexpf((float)m, -9);
    return (b & 0x80u) ? -v : v;
}
#endif

static __device__ __forceinline__ unsigned f32x4_to_fp8x4(float a, float b, float c, float d) {
#if FP8_HW
    int r = 0;
    r = __builtin_amdgcn_cvt_pk_fp8_f32(a, b, r, false);
    r = __builtin_amdgcn_cvt_pk_fp8_f32(c, d, r, true);
    return (unsigned)r;
#else
    return enc_fp8_sw(a) | (enc_fp8_sw(b) << 8) | (enc_fp8_sw(c) << 16) | (enc_fp8_sw(d) << 24);
#endif
}
// HI is a template constant so the builtin's word-select is an ICE.
template <bool HI>
static __device__ __forceinline__ f2_t fp8pk_to_f32(unsigned dw) {
#if FP8_HW
    return __builtin_amdgcn_cvt_pk_f32_fp8((int)dw, HI);
#else
    const unsigned lo = HI ? (dw >> 16) & 0xffu : dw & 0xffu;
    const unsigned hb = HI ? (dw >> 24) : (dw >> 8) & 0xffu;
    f2_t r; r[0] = dec_fp8_sw(lo); r[1] = dec_fp8_sw(hb);
    return r;
#endif
}

// Prologue: feats2[t][:] = fp8(feats[nid2[t]][:]); 16 rows/iter/wave, 4 gathers in flight.
// lane=(sub<<4)|c4; quarter-wave sub handles one row; lane covers 4 features -> 1 dword out.
__global__ __launch_bounds__(256) void k_cast8(
    const float* __restrict__ feats,  // [V,64] fp32
    const int*   __restrict__ nid2,   // [N2]
    unsigned*    __restrict__ feats2, // [N2,16] dwords (64 fp8)
    int N2)
{
    const int lane = threadIdx.x & 63;
    const int sub  = lane >> 4;
    const int c4   = lane & 15;
    const int gwave = blockIdx.x * (blockDim.x >> 6) + (threadIdx.x >> 6);
    const int nwave = gridDim.x * (blockDim.x >> 6);

    for (int base = 16 * gwave; base < N2; base += 16 * nwave) {
        int t[4]; bool vv[4]; int n[4];
#pragma unroll
        for (int s = 0; s < 4; ++s) {
            t[s]  = base + 4 * s + sub;
            vv[s] = t[s] < N2;
            n[s]  = vv[s] ? nid2[t[s]] : 0;
        }
        float4 a[4];
#pragma unroll
        for (int s = 0; s < 4; ++s)
            a[s] = ((const float4*)feats)[(size_t)n[s] * 16 + c4];
#pragma unroll
        for (int s = 0; s < 4; ++s) {
            const unsigned d = f32x4_to_fp8x4(a[s].x, a[s].y, a[s].z, a[s].w);
            if (vv[s]) feats2[(size_t)t[s] * 16 + c4] = d;
        }
    }
}

// Hop-1 (fp8 table): 2 output rows per wave-iter.
// lane = (hi<<5)|(g4<<3)|c8 : hi picks output row, g4 picks an 8-neighbor block,
// c8 picks an 8B chunk (8 fp8 = 8 features) of the gathered row -> dwordx2 gathers.
// Cross-iteration prefetch kept. W0 in LDS as packed-f16 pairs pre-scaled by 1/32.
__global__ __launch_bounds__(256, 4) void k_hop1_fp8(
    const unsigned* __restrict__ table, // [N2,16] dwords
    const float* __restrict__ W0,       // [64,64]
    const float* __restrict__ b0,       // [64]
    const int*   __restrict__ idx1,     // [N1,32]
    unsigned short* __restrict__ h1,    // [N1,64] f16 out
    int N1)
{
    __shared__ unsigned wlds[32 * 64];
    for (int e = threadIdx.x; e < 2048; e += 256) {
        const int p = e >> 6, l = e & 63;
        wlds[e] = pack_h2(W0[(2 * p) * 64 + l] * 0.03125f,
                          W0[(2 * p + 1) * 64 + l] * 0.03125f);
    }
    __syncthreads();

    const int lane = threadIdx.x & 63;
    const int g4   = (lane >> 3) & 3;
    const int hi   = lane >> 5;
    const int c8   = lane & 7;
    const float bias = b0[lane];
    const int gwave = blockIdx.x * (blockDim.x >> 6) + (threadIdx.x >> 6);
    const int nwave = gridDim.x * (blockDim.x >> 6);

    const int4*  iv = (const int4*)idx1;    // [N1, 8] int4
    const uint2* tp = (const uint2*)table;  // [N2, 8] uint2 (8B chunks)

    int base = 2 * gwave;
    if (base >= N1) return;

    uint2 v[8];
    {
        const int rr = (base + 1 < N1) ? base + hi : base;
        const int4 qa = iv[(size_t)rr * 8 + 2 * g4];
        const int4 qb = iv[(size_t)rr * 8 + 2 * g4 + 1];
        const int nk[8] = {qa.x, qa.y, qa.z, qa.w, qb.x, qb.y, qb.z, qb.w};
#pragma unroll
        for (int i = 0; i < 8; ++i)
            v[i] = tp[(size_t)nk[i] * 8 + c8];
    }

    for (;;) {
        const int nxt = base + 2 * nwave;
        const bool more = nxt < N1;
        uint2 w[8];
        if (more) {  // prefetch next iteration's gathers
            const int rr = (nxt + 1 < N1) ? nxt + hi : nxt;
            const int4 qa = iv[(size_t)rr * 8 + 2 * g4];
            const int4 qb = iv[(size_t)rr * 8 + 2 * g4 + 1];
            const int nk[8] = {qa.x, qa.y, qa.z, qa.w, qb.x, qb.y, qb.z, qb.w};
#pragma unroll
            for (int i = 0; i < 8; ++i)
                w[i] = tp[(size_t)nk[i] * 8 + c8];
        }

        // ---- consume current iteration: decode fp8, f32 accumulate ----
        float acc[8] = {0.f, 0.f, 0.f, 0.f, 0.f, 0.f, 0.f, 0.f};
#pragma unroll
        for (int i = 0; i < 8; ++i) {
            const f2_t p0 = fp8pk_to_f32<false>(v[i].x);
            const f2_t p1 = fp8pk_to_f32<true >(v[i].x);
            const f2_t p2 = fp8pk_to_f32<false>(v[i].y);
            const f2_t p3 = fp8pk_to_f32<true >(v[i].y);
            acc[0] += p0[0]; acc[1] += p0[1];
            acc[2] += p1[0]; acc[3] += p1[1];
            acc[4] += p2[0]; acc[5] += p2[1];
            acc[6] += p3[0]; acc[7] += p3[1];
        }
        // reduce across the 4 neighbor-groups (lanes stride 8, masks 8 and 16)
#pragma unroll
        for (int j = 0; j < 8; ++j) {
            acc[j] += __shfl_xor(acc[j], 8, 64);
            acc[j] += __shfl_xor(acc[j], 16, 64);
        }
        // pack pairs: pk4[j] = features (8*c8 + 2j, 8*c8 + 2j + 1) summed over 32 neighbors
        unsigned pk4[4];
#pragma unroll
        for (int j = 0; j < 4; ++j)
            pk4[j] = __builtin_bit_cast(unsigned,
                        __builtin_amdgcn_cvt_pkrtz(acc[2 * j], acc[2 * j + 1]));

        // lanes 0-31 hold row `base`, lanes 32-63 row `base+1`.
        float h0a = bias, h0b = 0.f, h1a = bias, h1b = 0.f;
#pragma unroll
        for (int p = 0; p < 32; ++p) {
            const unsigned wp = wlds[p * 64 + lane];
            const int av = (int)pk4[p & 3];
            const unsigned a0 = (unsigned)__builtin_amdgcn_readlane(av, p >> 2);
            const unsigned a1 = (unsigned)__builtin_amdgcn_readlane(av, 32 + (p >> 2));
            if (p & 1) { h0b = dot2f(a0, wp, h0b); h1b = dot2f(a1, wp, h1b); }
            else       { h0a = dot2f(a0, wp, h0a); h1a = dot2f(a1, wp, h1a); }
        }
        h1[(size_t)base * 64 + lane] = f2h_bits(fmaxf(h0a + h0b, 0.f));
        if (base + 1 < N1)
            h1[(size_t)(base + 1) * 64 + lane] = f2h_bits(fmaxf(h1a + h1b, 0.f));

        if (!more) break;
#pragma unroll
        for (int i = 0; i < 8; ++i) v[i] = w[i];
        base = nxt;
    }
}

// Fallback hop-1 (fp32 table, double indirection) — only if ws can't hold feats2.
__global__ __launch_bounds__(256) void k_hop1_f32(
    const float* __restrict__ table,  // feats fp32 [V,64]
    const float* __restrict__ W0,
    const float* __restrict__ b0,
    const int*   __restrict__ idx1,
    const int*   __restrict__ nid2,
    unsigned short* __restrict__ h1,
    int N1)
{
    const int lane = threadIdx.x & 63;
    const int sub  = lane >> 4;
    const int c4   = lane & 15;
    const int gwave = blockIdx.x * (blockDim.x >> 6) + (threadIdx.x >> 6);
    const int nwave = gridDim.x * (blockDim.x >> 6);

    unsigned w0p[32];
#pragma unroll
    for (int p = 0; p < 32; ++p)
        w0p[p] = pack_h2(W0[(2 * p) * 64 + lane] * 0.03125f,
                         W0[(2 * p + 1) * 64 + lane] * 0.03125f);
    const float bias = b0[lane];
    const int4* iv = (const int4*)idx1;

    for (int base = 2 * gwave; base < N1; base += 2 * nwave) {
        const int r0 = base;
        const bool has_r1 = (base + 1 < N1);
        const int r1 = has_r1 ? base + 1 : base;
        const int4 qa0 = iv[(size_t)r0 * 8 + 2 * sub];
        const int4 qb0 = iv[(size_t)r0 * 8 + 2 * sub + 1];
        const int4 qa1 = iv[(size_t)r1 * 8 + 2 * sub];
        const int4 qb1 = iv[(size_t)r1 * 8 + 2 * sub + 1];
        int nk0[8] = {qa0.x, qa0.y, qa0.z, qa0.w, qb0.x, qb0.y, qb0.z, qb0.w};
        int nk1[8] = {qa1.x, qa1.y, qa1.z, qa1.w, qb1.x, qb1.y, qb1.z, qb1.w};
#pragma unroll
        for (int i = 0; i < 8; ++i) { nk0[i] = nid2[nk0[i]]; nk1[i] = nid2[nk1[i]]; }

        float a0[4] = {0.f, 0.f, 0.f, 0.f};
        float a1[4] = {0.f, 0.f, 0.f, 0.f};
#pragma unroll
        for (int i = 0; i < 8; ++i) {
            const float4 v0 = ((const float4*)table)[(size_t)nk0[i] * 16 + c4];
            const float4 v1 = ((const float4*)table)[(size_t)nk1[i] * 16 + c4];
            a0[0] += v0.x; a0[1] += v0.y; a0[2] += v0.z; a0[3] += v0.w;
            a1[0] += v1.x; a1[1] += v1.y; a1[2] += v1.z; a1[3] += v1.w;
        }
#pragma unroll
        for (int c = 0; c < 4; ++c) {
            a0[c] += __shfl_xor(a0[c], 16, 64);
            a0[c] += __shfl_xor(a0[c], 32, 64);
            a1[c] += __shfl_xor(a1[c], 16, 64);
            a1[c] += __shfl_xor(a1[c], 32, 64);
        }
        const unsigned pk00 = __builtin_bit_cast(unsigned, __builtin_amdgcn_cvt_pkrtz(a0[0], a0[1]));
        const unsigned pk01 = __builtin_bit_cast(unsigned, __builtin_amdgcn_cvt_pkrtz(a0[2], a0[3]));
        const unsigned pk10 = __builtin_bit_cast(unsigned, __builtin_amdgcn_cvt_pkrtz(a1[0], a1[1]));
        const unsigned pk11 = __builtin_bit_cast(unsigned, __builtin_amdgcn_cvt_pkrtz(a1[2], a1[3]));

        float h0 = bias, h1v = bias;
#pragma unroll
        for (int p = 0; p < 32; ++p) {
            const unsigned a0p = (unsigned)__builtin_amdgcn_readlane(
                (int)(p & 1 ? pk01 : pk00), p >> 1);
            const unsigned a1p = (unsigned)__builtin_amdgcn_readlane(
                (int)(p & 1 ? pk11 : pk10), p >> 1);
            h0  = dot2f(a0p, w0p[p], h0);
            h1v = dot2f(a1p, w0p[p], h1v);
        }
        h1[(size_t)r0 * 64 + lane] = f2h_bits(fmaxf(h0, 0.f));
        if (has_r1) h1[(size_t)r1 * 64 + lane] = f2h_bits(fmaxf(h1v, 0.f));
    }
}

// Seed layer: gather-mean over f16 h1 rows (packed adds), W1 via dot2, fp32 out.
__global__ __launch_bounds__(256, 4) void k_hop0(
    const unsigned short* __restrict__ h1t,  // [N1,64] f16
    const float* __restrict__ W1,            // [64,64]
    const float* __restrict__ b1,            // [64]
    const int*   __restrict__ idx0,          // [N0,32]
    float*       __restrict__ out,           // [N0,64] fp32
    int N0)
{
    __shared__ unsigned wlds[32 * 64];
    for (int e = threadIdx.x; e < 2048; e += 256) {
        const int p = e >> 6, l = e & 63;
        wlds[e] = pack_h2(W1[(2 * p) * 64 + l] * 0.03125f,
                          W1[(2 * p + 1) * 64 + l] * 0.03125f);
    }
    __syncthreads();

    const int lane = threadIdx.x & 63;
    const int g4   = (lane >> 3) & 3;
    const int hi   = lane >> 5;
    const int c8   = lane & 7;
    const float bias = b1[lane];
    const int gwave = blockIdx.x * (blockDim.x >> 6) + (threadIdx.x >> 6);
    const int nwave = gridDim.x * (blockDim.x >> 6);

    const int4*  iv = (const int4*)idx0;
    const uint4* tp = (const uint4*)h1t;

    for (int base = 2 * gwave; base < N0; base += 2 * nwave) {
        const int rr = (base + 1 < N0) ? base + hi : base;
        const int4 qa = iv[(size_t)rr * 8 + 2 * g4];
        const int4 qb = iv[(size_t)rr * 8 + 2 * g4 + 1];
        const int nk[8] = {qa.x, qa.y, qa.z, qa.w, qb.x, qb.y, qb.z, qb.w};

        uint4 v[8];
#pragma unroll
        for (int i = 0; i < 8; ++i)
            v[i] = tp[(size_t)nk[i] * 8 + c8];

        h2_t acc[4] = {h2_t{0, 0}, h2_t{0, 0}, h2_t{0, 0}, h2_t{0, 0}};
#pragma unroll
        for (int i = 0; i < 8; ++i) {
            acc[0] += __builtin_bit_cast(h2_t, v[i].x);
            acc[1] += __builtin_bit_cast(h2_t, v[i].y);
            acc[2] += __builtin_bit_cast(h2_t, v[i].z);
            acc[3] += __builtin_bit_cast(h2_t, v[i].w);
        }
#pragma unroll
        for (int j = 0; j < 4; ++j) {
            acc[j] += __builtin_bit_cast(h2_t, __shfl_xor(__builtin_bit_cast(int, acc[j]), 8, 64));
            acc[j] += __builtin_bit_cast(h2_t, __shfl_xor(__builtin_bit_cast(int, acc[j]), 16, 64));
        }
        float o0a = bias, o0b = 0.f, o1a = bias, o1b = 0.f;
#pragma unroll
        for (int p = 0; p < 32; ++p) {
            const unsigned wp = wlds[p * 64 + lane];
            const int av = __builtin_bit_cast(int, acc[p & 3]);
            const unsigned a0 = (unsigned)__builtin_amdgcn_readlane(av, p >> 2);
            const unsigned a1 = (unsigned)__builtin_amdgcn_readlane(av, 32 + (p >> 2));
            if (p & 1) { o0b = dot2f(a0, wp, o0b); o1b = dot2f(a1, wp, o1b); }
            else       { o0a = dot2f(a0, wp, o0a); o1a = dot2f(a1, wp, o1a); }
        }
        out[(size_t)base * 64 + lane] = fmaxf(o0a + o0b, 0.f);
        if (base + 1 < N0)
            out[(size_t)(base + 1) * 64 + lane] = fmaxf(o1a + o1b, 0.f);
    }
}

extern "C" void kernel_launch(void* const* d_in, const int* in_sizes, int n_in,
                              void* d_out, int out_size, void* d_ws, size_t ws_size,
                              hipStream_t stream) {
    const float* feats = (const float*)d_in[0];
    const float* W0    = (const float*)d_in[1];
    const float* b0    = (const float*)d_in[2];
    const float* W1    = (const float*)d_in[3];
    const float* b1    = (const float*)d_in[4];
    const int*   idx0  = (const int*)d_in[5];   // [N0,32]
    const int*   idx1  = (const int*)d_in[6];   // [N1,32]
    // d_in[7] = node_ids1 — dead in the reference (v1 unused)
    const int*   nid2  = (const int*)d_in[8];   // [N2]

    const int N0 = in_sizes[5] / 32;            // 8192
    const int N1 = in_sizes[6] / 32;            // 100000
    const int N2 = in_sizes[8];                 // 300000

    const size_t bytes_feats2 = (size_t)N2 * 64;       // fp8: 19.2 MB
    const size_t bytes_h1     = (size_t)N1 * 64 * 2;   // f16: 12.8 MB

    if (ws_size >= bytes_feats2 + bytes_h1) {
        unsigned*       feats2 = (unsigned*)d_ws;
        unsigned short* h1     = (unsigned short*)((char*)d_ws + bytes_feats2);
        k_cast8<<<2048, 256, 0, stream>>>(feats, nid2, feats2, N2);
        k_hop1_fp8<<<2048, 256, 0, stream>>>(feats2, W0, b0, idx1, h1, N1);
        k_hop0<<<1024, 256, 0, stream>>>(h1, W1, b1, idx0, (float*)d_out, N0);
    } else {
        unsigned short* h1 = (unsigned short*)d_ws;
        k_hop1_f32<<<2048, 256, 0, stream>>>(feats, W0, b0, idx1, nid2, h1, N1);
        k_hop0<<<1024, 256, 0, stream>>>(h1, W1, b1, idx0, (float*)d_out, N0);
    }
}